// Round 3
// baseline (215.929 us; speedup 1.0000x reference)
//
#include <hip/hip_runtime.h>

// Discriminator fused pipeline, R3.
//  kB : precompute MFMA A-fragments (bf16 weights) for lc1/lc2/lc3 + zero stats.
//  k1 : conv1 (packed-fp32 v_pk_fma) + lc1 via mfma_f32_16x16x32_bf16.
//       Writes y1 bf16 [800][8192] + BN1 stats.
//  k2 : lc2 as MFMA: K=64=(16c x 4t), M=16 (rows 8-15 zero). BN1 folded into
//       per-lane (a',b') on bf16 loads. Writes y2 bf16 [528][8192] + BN2 stats.
//  k3 : lc3 as MFMA: K=32=(8c x 4t). Writes y3 bf16 [384][8192] + BN3 stats.
//  k4 : BN3 affine + transpose -> out[8192][384] f32.
// All grids use blockIdx.x = 256-sample chunk so chunk c -> XCD c%8 (L2 locality).

typedef float  f32x4 __attribute__((ext_vector_type(4)));
typedef float  f32x2 __attribute__((ext_vector_type(2)));
typedef short  bf16x8 __attribute__((ext_vector_type(8)));

union FR  { int4 i4; bf16x8 bf; unsigned u[4]; };
union F2U { f32x2 v; unsigned u[2]; float f[2]; };

#define LRELU(v) fmaxf((v), 0.01f * (v))

// pack two fp32 -> packed bf16 (truncation), one v_perm_b32
static __device__ inline unsigned pk2(float hi, float lo) {
    return __builtin_amdgcn_perm(__float_as_uint(hi), __float_as_uint(lo), 0x07060302u);
}
// RNE fp32->bf16
static __device__ inline unsigned bfr(float f) {
    unsigned u = __float_as_uint(f);
    return (u + 0x7fffu + ((u >> 16) & 1u)) >> 16;
}
static __device__ inline unsigned short bfr16(float f) { return (unsigned short)bfr(f); }

#if __has_builtin(__builtin_elementwise_fma)
static __device__ inline f32x2 pk_fma(f32x2 a, f32x2 b, f32x2 c) { return __builtin_elementwise_fma(a, b, c); }
#else
static __device__ inline f32x2 pk_fma(f32x2 a, f32x2 b, f32x2 c) { return a * b + c; }
#endif
static __device__ inline f32x2 pk_lrelu(f32x2 v) {
#if __has_builtin(__builtin_elementwise_max)
    return __builtin_elementwise_max(v, v * 0.01f);
#else
    f32x2 r; r.x = LRELU(v.x); r.y = LRELU(v.y); return r;
#endif
}

// ---------------- kB: A-fragment precompute + stats zero ----------------
// grid.x: [0,50) lc1 pos | [50,116) lc2 pos | [116,164) lc3 pos
__global__ __launch_bounds__(256) void kB_frags(
    const float* __restrict__ lw1,   // [16][64][450]
    const float* __restrict__ lw2,   // [8][16][264]
    const float* __restrict__ lw3,   // [8][8][192]
    int4* __restrict__ afg1, int4* __restrict__ afg2, int4* __restrict__ afg3,
    float* __restrict__ stats)
{
    const int bx = blockIdx.x, tid = threadIdx.x;
    if (bx == 0 && tid < 64) stats[tid] = 0.0f;

    if (bx < 50) {
        const int pos = bx;
        __shared__ float wt[9216];           // [pair=o*64+c][t=0..8]
        for (int e = tid; e < 9216; e += 256) {
            int pair = e / 9, t = e - 9 * pair;
            wt[e] = lw1[pair * 450 + pos * 9 + t];
        }
        __syncthreads();
        for (int e = tid; e < 1152; e += 256) {
            int l = e & 63, ht = e >> 6;
            int h = ht / 9, t = ht - 9 * h;
            int q = l >> 4, o = l & 15;
            unsigned uu[4];
            #pragma unroll
            for (int p = 0; p < 4; ++p) {
                int c0 = 32 * h + 8 * q + 2 * p;
                float w0 = wt[(o * 64 + c0) * 9 + t];
                float w1 = wt[(o * 64 + c0 + 1) * 9 + t];
                uu[p] = bfr(w0) | (bfr(w1) << 16);
            }
            int4 st = { (int)uu[0], (int)uu[1], (int)uu[2], (int)uu[3] };
            afg1[pos * 1152 + e] = st;
        }
    } else if (bx < 116) {
        const int pos = bx - 50;
        if (tid < 128) {
            int l = tid & 63, h = tid >> 6;
            int q = l >> 4, o = l & 15;
            unsigned uu[4];
            #pragma unroll
            for (int p = 0; p < 4; ++p) {
                unsigned w01[2];
                #pragma unroll
                for (int d = 0; d < 2; ++d) {
                    int kg = h * 32 + q * 8 + 2 * p + d;
                    int c = kg >> 2, t = kg & 3;
                    float w = (o < 8) ? lw2[(o * 16 + c) * 264 + pos * 4 + t] : 0.0f;
                    w01[d] = bfr(w);
                }
                uu[p] = w01[0] | (w01[1] << 16);
            }
            int4 st = { (int)uu[0], (int)uu[1], (int)uu[2], (int)uu[3] };
            afg2[(pos * 2 + h) * 64 + l] = st;
        }
    } else {
        const int pos = bx - 116;
        if (tid < 64) {
            int l = tid, q = l >> 4, o = l & 15;
            unsigned uu[4];
            #pragma unroll
            for (int p = 0; p < 4; ++p) {
                unsigned w01[2];
                #pragma unroll
                for (int d = 0; d < 2; ++d) {
                    int kg = q * 8 + 2 * p + d;
                    int c = kg >> 2, t = kg & 3;
                    float w = (o < 8) ? lw3[(o * 8 + c) * 192 + pos * 4 + t] : 0.0f;
                    w01[d] = bfr(w);
                }
                uu[p] = w01[0] | (w01[1] << 16);
            }
            int4 st = { (int)uu[0], (int)uu[1], (int)uu[2], (int)uu[3] };
            afg3[pos * 64 + l] = st;
        }
    }
}

// ---------------- k1: conv1 + lc1 (MFMA) ----------------
__global__ __launch_bounds__(256) void k1_lc1(
    const float* __restrict__ img,   // [8192*90]
    const float* __restrict__ cw,    // conv1_w [64*4]
    const float* __restrict__ cb,    // conv1_b [64]
    const int4* __restrict__ afg,    // lc1 A-frags
    const float* __restrict__ lb,    // lc1_b [16*50]
    unsigned short* __restrict__ y1b,// bf16 [800][8192]
    float* __restrict__ stats)       // [0..31] sum16/sq16
{
    __shared__ int4   AfL[1152];     // 18432 B
    __shared__ float4 cw4s[64];
    __shared__ float  cbl[64];
    __shared__ float  bl[16];
    __shared__ float  red[32];

    const int pos = blockIdx.y;           // 0..49
    const int oh = pos / 5, ow = pos % 5;
    const int tid = threadIdx.x;
    const int wv = tid >> 6, lane = tid & 63;
    const int lane15 = lane & 15, q = lane >> 4;

    for (int e = tid; e < 1152; e += 256) AfL[e] = afg[pos * 1152 + e];
    if (tid < 64) { cw4s[tid] = ((const float4*)cw)[tid]; cbl[tid] = cb[tid]; }
    if (tid < 16) bl[tid] = lb[tid * 50 + pos];
    if (tid < 32) red[tid] = 0.0f;
    __syncthreads();

    bool km[9];
    #pragma unroll
    for (int i = 0; i < 3; i++)
        #pragma unroll
        for (int j = 0; j < 3; j++) {
            int r = oh + i - 1, c2 = 2 * ow + j - 1;
            km[i * 3 + j] = (r >= 0 && r < 10 && c2 >= 0 && c2 < 9);
        }

    const int sBase = blockIdx.x * 256 + wv * 64;
    float ip[4][16];
    #pragma unroll
    for (int g = 0; g < 4; ++g) {
        const float* ib = img + (size_t)(sBase + g * 16 + lane15) * 90;
        #pragma unroll
        for (int a = 0; a < 4; ++a) {
            int r = oh - 1 + a;
            bool rok = (r >= 0 && r < 10);
            #pragma unroll
            for (int d = 0; d < 4; ++d) {
                int c2 = 2 * ow - 1 + d;
                bool ok = rok && (c2 >= 0 && c2 < 9);
                ip[g][a * 4 + d] = ok ? ib[r * 9 + c2] : 0.0f;
            }
        }
    }

    f32x4 acc[4];
    #pragma unroll
    for (int g = 0; g < 4; ++g) acc[g] = (f32x4){0.f, 0.f, 0.f, 0.f};

    #pragma unroll
    for (int h = 0; h < 2; ++h) {
        // channel-paired conv1 weights (packed fp32 operands)
        f32x2 wx2[4], wy2[4], wz2[4], ww2[4], cb2[4];
        #pragma unroll
        for (int p = 0; p < 4; ++p) {
            float4 wa = cw4s[h * 32 + q * 8 + 2 * p];
            float4 wb = cw4s[h * 32 + q * 8 + 2 * p + 1];
            wx2[p] = (f32x2){wa.x, wb.x};
            wy2[p] = (f32x2){wa.y, wb.y};
            wz2[p] = (f32x2){wa.z, wb.z};
            ww2[p] = (f32x2){wa.w, wb.w};
            cb2[p] = (f32x2){cbl[h * 32 + q * 8 + 2 * p], cbl[h * 32 + q * 8 + 2 * p + 1]};
        }
        #pragma unroll
        for (int t = 0; t < 9; ++t) {
            const int ti = t / 3, tj = t % 3;
            const int i0 = ti * 4 + tj;
            if (km[t]) {
                FR fa; fa.i4 = AfL[(h * 9 + t) * 64 + lane];
                #pragma unroll
                for (int g = 0; g < 4; ++g) {
                    f32x2 s0 = (f32x2)ip[g][i0];
                    f32x2 s1 = (f32x2)ip[g][i0 + 1];
                    f32x2 s2 = (f32x2)ip[g][i0 + 4];
                    f32x2 s3 = (f32x2)ip[g][i0 + 5];
                    FR fb;
                    #pragma unroll
                    for (int p = 0; p < 4; ++p) {
                        f32x2 v = pk_fma(s0, wx2[p], cb2[p]);
                        v = pk_fma(s1, wy2[p], v);
                        v = pk_fma(s2, wz2[p], v);
                        v = pk_fma(s3, ww2[p], v);
                        v = pk_lrelu(v);
                        F2U u; u.v = v;
                        fb.u[p] = __builtin_amdgcn_perm(u.u[1], u.u[0], 0x07060302u);
                    }
                    acc[g] = __builtin_amdgcn_mfma_f32_16x16x32_bf16(fa.bf, fb.bf, acc[g], 0, 0, 0);
                }
            }
        }
    }

    float so[4], sq[4];
    #pragma unroll
    for (int r = 0; r < 4; ++r) { so[r] = 0.f; sq[r] = 0.f; }
    #pragma unroll
    for (int g = 0; g < 4; ++g) {
        #pragma unroll
        for (int r = 0; r < 4; ++r) {
            int o = q * 4 + r;
            float v = acc[g][r] + bl[o];
            v = LRELU(v);
            y1b[(size_t)(o * 50 + pos) * 8192 + sBase + g * 16 + lane15] = bfr16(v);
            so[r] += v; sq[r] += v * v;
        }
    }
    #pragma unroll
    for (int r = 0; r < 4; ++r) {
        #pragma unroll
        for (int m = 1; m < 16; m <<= 1) {
            so[r] += __shfl_xor(so[r], m, 16);
            sq[r] += __shfl_xor(sq[r], m, 16);
        }
        if (lane15 == 0) {
            int o = q * 4 + r;
            atomicAdd(&red[o], so[r]);
            atomicAdd(&red[16 + o], sq[r]);
        }
    }
    __syncthreads();
    if (tid < 32) atomicAdd(&stats[tid], red[tid]);
}

// ---------------- k2: lc2 as MFMA (K=64) ----------------
__global__ __launch_bounds__(256) void k2_lc2(
    const unsigned short* __restrict__ y1b,  // bf16 [800][8192]
    const int4* __restrict__ afg2,
    const float* __restrict__ lb,    // lc2_b [8*66]
    const float* __restrict__ g1, const float* __restrict__ be1,
    unsigned short* __restrict__ y2b,        // bf16 [528][8192]
    float* __restrict__ stats)
{
    __shared__ float a1L[16], b1L[16];
    __shared__ float blL[16];
    __shared__ float red[16];

    const int pos = blockIdx.y;          // 0..65
    const int oh = pos / 6, ow = pos % 6;
    const int tid = threadIdx.x;
    const int wv = tid >> 6, lane = tid & 63;
    const int lane15 = lane & 15, q = lane >> 4;

    if (tid < 16) {
        float m = stats[tid] * (1.0f / 409600.0f);
        float v = stats[16 + tid] * (1.0f / 409600.0f) - m * m;
        float a = g1[tid] * rsqrtf(v + 1e-5f);
        a1L[tid] = a; b1L[tid] = be1[tid] - a * m;
        blL[tid] = (tid < 8) ? lb[tid * 66 + pos] : 0.0f;
        red[tid] = 0.0f;
    }
    FR fa[2];
    fa[0].i4 = afg2[(pos * 2 + 0) * 64 + lane];
    fa[1].i4 = afg2[(pos * 2 + 1) * 64 + lane];
    __syncthreads();

    // per-lane (a',b') and row offsets for its 16 k-slots
    float aa[2][8], bb[2][8];
    unsigned off[2][8];
    #pragma unroll
    for (int h = 0; h < 2; ++h)
        #pragma unroll
        for (int j = 0; j < 8; ++j) {
            int kg = h * 32 + q * 8 + j;
            int c = kg >> 2, t = kg & 3;
            int r = oh + (t >> 1) - 1, c2 = ow + (t & 1) - 1;
            bool ok = (r >= 0 && r < 10 && c2 >= 0 && c2 < 5);
            int rc = min(max(r, 0), 9), cc2 = min(max(c2, 0), 4);
            off[h][j] = (unsigned)((c * 50 + rc * 5 + cc2) * 8192);
            aa[h][j] = ok ? a1L[c] : 0.0f;
            bb[h][j] = ok ? b1L[c] : 0.0f;
        }

    const int sWave = blockIdx.x * 256 + wv * 64;
    f32x4 acc[4];
    #pragma unroll
    for (int g = 0; g < 4; ++g) acc[g] = (f32x4){0.f, 0.f, 0.f, 0.f};

    #pragma unroll
    for (int g = 0; g < 4; ++g) {
        const unsigned samp = (unsigned)(sWave + g * 16 + lane15);
        #pragma unroll
        for (int h = 0; h < 2; ++h) {
            FR fb;
            #pragma unroll
            for (int p = 0; p < 4; ++p) {
                int j0 = 2 * p, j1 = 2 * p + 1;
                float x0 = __uint_as_float((unsigned)y1b[off[h][j0] + samp] << 16);
                float x1 = __uint_as_float((unsigned)y1b[off[h][j1] + samp] << 16);
                float p0 = fmaf(aa[h][j0], x0, bb[h][j0]);
                float p1 = fmaf(aa[h][j1], x1, bb[h][j1]);
                fb.u[p] = pk2(p1, p0);
            }
            acc[g] = __builtin_amdgcn_mfma_f32_16x16x32_bf16(fa[h].bf, fb.bf, acc[g], 0, 0, 0);
        }
    }

    float so[4], sq[4];
    #pragma unroll
    for (int r = 0; r < 4; ++r) { so[r] = 0.f; sq[r] = 0.f; }
    #pragma unroll
    for (int g = 0; g < 4; ++g) {
        #pragma unroll
        for (int r = 0; r < 4; ++r) {
            int row = q * 4 + r;                 // valid rows 0..7 (lanes<32)
            float v = acc[g][r] + blL[row & 15];
            v = LRELU(v);
            if (lane < 32)
                y2b[(size_t)(row * 66 + pos) * 8192 + sWave + g * 16 + lane15] = bfr16(v);
            so[r] += v; sq[r] += v * v;
        }
    }
    #pragma unroll
    for (int r = 0; r < 4; ++r) {
        #pragma unroll
        for (int m = 1; m < 16; m <<= 1) {
            so[r] += __shfl_xor(so[r], m, 16);
            sq[r] += __shfl_xor(sq[r], m, 16);
        }
        if (lane15 == 0 && lane < 32) {
            int row = q * 4 + r;
            atomicAdd(&red[row], so[r]);
            atomicAdd(&red[8 + row], sq[r]);
        }
    }
    __syncthreads();
    if (tid < 16) atomicAdd(&stats[32 + tid], red[tid]);
}

// ---------------- k3: lc3 as MFMA (K=32) ----------------
__global__ __launch_bounds__(256) void k3_lc3(
    const unsigned short* __restrict__ y2b,  // bf16 [528][8192]
    const int4* __restrict__ afg3,
    const float* __restrict__ lb,    // lc3_b [8*48]
    const float* __restrict__ g2, const float* __restrict__ be2,
    unsigned short* __restrict__ y3b,        // bf16 [384][8192]
    float* __restrict__ stats)
{
    __shared__ float a2L[8], b2L[8];
    __shared__ float blL[16];
    __shared__ float red[16];

    const int pos = blockIdx.y;          // 0..47
    const int oh = pos >> 2, ow = pos & 3;
    const int tid = threadIdx.x;
    const int wv = tid >> 6, lane = tid & 63;
    const int lane15 = lane & 15, q = lane >> 4;

    if (tid < 16) {
        if (tid < 8) {
            float m = stats[32 + tid] * (1.0f / 540672.0f);
            float v = stats[40 + tid] * (1.0f / 540672.0f) - m * m;
            float a = g2[tid] * rsqrtf(v + 1e-5f);
            a2L[tid] = a; b2L[tid] = be2[tid] - a * m;
        }
        blL[tid] = (tid < 8) ? lb[tid * 48 + pos] : 0.0f;
        red[tid] = 0.0f;
    }
    FR fa; fa.i4 = afg3[pos * 64 + lane];
    __syncthreads();

    float aa[8], bb[8];
    unsigned off[8];
    #pragma unroll
    for (int j = 0; j < 8; ++j) {
        int kg = q * 8 + j;
        int c = kg >> 2, t = kg & 3;
        int r = oh + (t >> 1) - 1, c2 = 2 * ow + (t & 1) - 1;
        bool ok = (r >= 0 && r < 11 && c2 >= 0 && c2 < 6);
        int rc = min(max(r, 0), 10), cc2 = min(max(c2, 0), 5);
        off[j] = (unsigned)((c * 66 + rc * 6 + cc2) * 8192);
        aa[j] = ok ? a2L[c] : 0.0f;
        bb[j] = ok ? b2L[c] : 0.0f;
    }

    const int sWave = blockIdx.x * 256 + wv * 64;
    f32x4 acc[4];
    #pragma unroll
    for (int g = 0; g < 4; ++g) acc[g] = (f32x4){0.f, 0.f, 0.f, 0.f};

    #pragma unroll
    for (int g = 0; g < 4; ++g) {
        const unsigned samp = (unsigned)(sWave + g * 16 + lane15);
        FR fb;
        #pragma unroll
        for (int p = 0; p < 4; ++p) {
            int j0 = 2 * p, j1 = 2 * p + 1;
            float x0 = __uint_as_float((unsigned)y2b[off[j0] + samp] << 16);
            float x1 = __uint_as_float((unsigned)y2b[off[j1] + samp] << 16);
            float p0 = fmaf(aa[j0], x0, bb[j0]);
            float p1 = fmaf(aa[j1], x1, bb[j1]);
            fb.u[p] = pk2(p1, p0);
        }
        acc[g] = __builtin_amdgcn_mfma_f32_16x16x32_bf16(fa.bf, fb.bf, acc[g], 0, 0, 0);
    }

    float so[4], sq[4];
    #pragma unroll
    for (int r = 0; r < 4; ++r) { so[r] = 0.f; sq[r] = 0.f; }
    #pragma unroll
    for (int g = 0; g < 4; ++g) {
        #pragma unroll
        for (int r = 0; r < 4; ++r) {
            int row = q * 4 + r;
            float v = acc[g][r] + blL[row & 15];
            v = LRELU(v);
            if (lane < 32)
                y3b[(size_t)(row * 48 + pos) * 8192 + sWave + g * 16 + lane15] = bfr16(v);
            so[r] += v; sq[r] += v * v;
        }
    }
    #pragma unroll
    for (int r = 0; r < 4; ++r) {
        #pragma unroll
        for (int m = 1; m < 16; m <<= 1) {
            so[r] += __shfl_xor(so[r], m, 16);
            sq[r] += __shfl_xor(sq[r], m, 16);
        }
        if (lane15 == 0 && lane < 32) {
            int row = q * 4 + r;
            atomicAdd(&red[row], so[r]);
            atomicAdd(&red[8 + row], sq[r]);
        }
    }
    __syncthreads();
    if (tid < 16) atomicAdd(&stats[48 + tid], red[tid]);
}

// ---------------- k4: BN3 + transpose ----------------
__global__ __launch_bounds__(256) void k4_out(
    const unsigned short* __restrict__ y3b,  // bf16 [384][8192]
    const float* __restrict__ g3, const float* __restrict__ be3,
    const float* __restrict__ stats,
    float* __restrict__ out)                 // [8192][384]
{
    __shared__ float tile[64][65];
    __shared__ float a3[8], b3[8];
    const int tid = threadIdx.x;
    if (tid < 8) {
        float m = stats[48 + tid] * (1.0f / 393216.0f);
        float v = stats[56 + tid] * (1.0f / 393216.0f) - m * m;
        float a = g3[tid] * rsqrtf(v + 1e-5f);
        a3[tid] = a; b3[tid] = be3[tid] - a * m;
    }
    __syncthreads();

    const int ftile = blockIdx.y >> 2, sub = blockIdx.y & 3;
    const int fbase = ftile * 64;
    const int sbase = blockIdx.x * 256 + sub * 64;

    #pragma unroll
    for (int rep = 0; rep < 16; rep++) {
        int idx = rep * 256 + tid;
        int f = idx >> 6, s = idx & 63;
        int ff = fbase + f;
        int o = ff / 48;
        float x = __uint_as_float((unsigned)y3b[(size_t)ff * 8192 + sbase + s] << 16);
        tile[f][s] = a3[o] * x + b3[o];
    }
    __syncthreads();
    #pragma unroll
    for (int rep = 0; rep < 16; rep++) {
        int idx = rep * 256 + tid;
        int s = idx >> 6, f = idx & 63;
        out[(size_t)(sbase + s) * 384 + fbase + f] = tile[f][s];
    }
}

extern "C" void kernel_launch(void* const* d_in, const int* in_sizes, int n_in,
                              void* d_out, int out_size, void* d_ws, size_t ws_size,
                              hipStream_t stream) {
    const float* image   = (const float*)d_in[0];
    const float* conv1_w = (const float*)d_in[1];
    const float* conv1_b = (const float*)d_in[2];
    const float* lc1_w   = (const float*)d_in[3];
    const float* lc1_b   = (const float*)d_in[4];
    const float* lc2_w   = (const float*)d_in[5];
    const float* lc2_b   = (const float*)d_in[6];
    const float* lc3_w   = (const float*)d_in[7];
    const float* lc3_b   = (const float*)d_in[8];
    const float* gamma1  = (const float*)d_in[9];
    const float* beta1   = (const float*)d_in[10];
    const float* gamma2  = (const float*)d_in[11];
    const float* beta2   = (const float*)d_in[12];
    const float* gamma3  = (const float*)d_in[13];
    const float* beta3   = (const float*)d_in[14];

    char* wsb = (char*)d_ws;
    float*          stats = (float*)wsb;                       // 64 f
    unsigned short* y1b   = (unsigned short*)(wsb + 1024);     // 800*8192*2  = 13107200
    unsigned short* y2b   = (unsigned short*)(wsb + 13108224); // 528*8192*2  = 8650752
    unsigned short* y3b   = (unsigned short*)(wsb + 21758976); // 384*8192*2  = 6291456
    int4*           afg1  = (int4*)(wsb + 28050432);           // 57600*16    = 921600
    int4*           afg2  = (int4*)(wsb + 28972032);           // 8448*16     = 135168
    int4*           afg3  = (int4*)(wsb + 29107200);           // 3072*16     = 49152

    kB_frags<<<dim3(164),     dim3(256), 0, stream>>>(lc1_w, lc2_w, lc3_w,
                                                      afg1, afg2, afg3, stats);
    k1_lc1  <<<dim3(32, 50),  dim3(256), 0, stream>>>(image, conv1_w, conv1_b,
                                                      afg1, lc1_b, y1b, stats);
    k2_lc2  <<<dim3(32, 66),  dim3(256), 0, stream>>>(y1b, afg2, lc2_b,
                                                      gamma1, beta1, y2b, stats);
    k3_lc3  <<<dim3(32, 48),  dim3(256), 0, stream>>>(y2b, afg3, lc3_b,
                                                      gamma2, beta2, y3b, stats);
    k4_out  <<<dim3(32, 24),  dim3(256), 0, stream>>>(y3b, gamma3, beta3, stats,
                                                      (float*)d_out);
}